// Round 14
// baseline (217.206 us; speedup 1.0000x reference)
//
#include <hip/hip_runtime.h>
#include <stdint.h>

// FractalImage: B=16, 224x224, k=3+2*kidx, kidx in [0,50), 3 metrics.
// Chebyshev: data-independent (x in [0,1)) -> analytic in finalize.
// kidx<=6: direct per-pixel r-loop (runtime R<=7), exp-recurrence sigmoid.
// kidx>=7: MERGED disc list (r12 zones, verbatim math). Round-14:
//   * P<=16 classes (kidx>=21): BLOCK-MODE -- 4 waves split one patch's
//     pairs (stride 4), LDS combine. Heavy block wall 13us -> ~3us.
//   * T halved to 5000 (finer wave-mode blocks for packing).
//   * finalize logf -> __log2f * ln2.

#define L2E4f 5.770780163555854f    // 4*log2(e)
#define QE4f  0.0183156388887342f   // e^-4

struct Tabs {
  int gpre[51];
  int CH[50];
  int kofseq[50];
  int GT;
  int eoff[18], ecnt[18];   // merged list offset (u32 words) / padded count (x128)
  int moff[18], mcnt[18];   // per-pair meta offset / count
  int pbase;                // partial-slot base (float index into ws)
};

__device__ __constant__ float LXT[20] = {
  0.0f, 0.69314718f, 1.09861229f, 1.38629436f, 1.60943791f,
  1.79175947f, 1.94591015f, 2.07944154f, 2.19722458f, 2.30258509f,
  2.39789527f, 2.48490665f, 2.56494936f, 2.63905733f, 2.70805020f,
  2.77258872f, 2.83321334f, 2.89037176f, 2.94443898f, 2.99573227f};

// e^{4r} and e^{-4r}, r=0..20 (static-indexed -> immediates)
constexpr float PRt[21] = {1.0f,
  5.45981500e1f, 2.98095799e3f, 1.62754791e5f, 8.88611052e6f, 4.85165195e8f,
  2.64891221e10f, 1.44625706e12f, 7.89629602e13f, 4.31123155e15f, 2.35385267e17f,
  1.28516001e19f, 7.01673591e20f, 3.83100800e22f, 2.09165950e24f, 1.14200739e26f,
  6.23514908e27f, 3.40427605e29f, 1.85867175e31f, 1.01480039e33f, 5.54062238e34f};
constexpr float QRt[21] = {1.0f,
  1.83156389e-2f, 3.35462628e-4f, 6.14421235e-6f, 1.12535175e-7f, 2.06115362e-9f,
  3.77513454e-11f, 6.91440011e-13f, 1.26641655e-14f, 2.31952283e-16f, 4.24835426e-18f,
  7.78113224e-20f, 1.42516408e-21f, 2.61027907e-23f, 4.78089288e-25f, 8.75651076e-27f,
  1.60381089e-28f, 2.93748211e-30f, 5.38018616e-32f, 9.85415469e-34f, 1.80485139e-35f};

__device__ __forceinline__ float wred64(float v) {
#pragma unroll
  for (int off = 32; off > 0; off >>= 1) v += __shfl_xor(v, off, 64);
  return v;
}

__device__ __forceinline__ int csqrt_d(int v) {   // smallest x>=0 with x*x>=v
  if (v <= 0) return 0;
  int x = (int)sqrtf((float)v);
  while (x * x < v) ++x;
  while (x > 0 && (x - 1) * (x - 1) >= v) --x;
  return x;
}

__device__ __forceinline__ int eaddr(uint32_t e, int c) {
  return (c + (int)((e >> 8) & 255) - 32) * 224 + (c + (int)(e & 255) - 32);
}

// ------------------- merged list builder (18 blocks, one per class) -------------------
__global__ __launch_bounds__(256) void build_lists(uint32_t* ws, Tabs tab) {
  const int ci = (int)blockIdx.x;
  const int c_eff = 8 + ci;
  const int cb = (c_eff < 24) ? c_eff : 24;
  const int Rcl = (c_eff < 20) ? c_eff : 20;
  const int amax = (Rcl + 4 < 24) ? Rcl + 4 : 24;
  const int W = 2 * cb + 1;
  const int tid = (int)threadIdx.x;
  __shared__ int rs[25 * 49];
  __shared__ int abase[26];
  uint32_t* dst = ws + tab.eoff[ci];

  for (int pid = tid; pid < (amax + 1) * W; pid += 256) {
    const int a = pid / W, iy = pid % W - cb;
    const int B = (a + 1) * (a + 1) - iy * iy;
    int len = 0;
    if (B > 0) {
      const int A = a * a - iy * iy;
      const int x0 = csqrt_d(A);
      int x1 = csqrt_d(B); if (x1 > cb + 1) x1 = cb + 1;
      if (x1 > x0) len = (x0 == 0) ? (2 * x1 - 1) : 2 * (x1 - x0);
    }
    rs[pid] = len;
  }
  __syncthreads();
  if (tid <= amax) {
    int acc = 0;
    for (int iyi = 0; iyi < W; ++iyi) { const int L = rs[tid * W + iyi]; rs[tid * W + iyi] = acc; acc += L; }
    abase[tid + 1] = acc;
  }
  __syncthreads();
  if (tid == 0) { abase[0] = 0; for (int a = 1; a <= amax + 1; ++a) abase[a] += abase[a - 1]; }
  __syncthreads();
  for (int pid = tid; pid < (amax + 1) * W; pid += 256) {
    const int a = pid / W, iy = pid % W - cb;
    const int B = (a + 1) * (a + 1) - iy * iy;
    if (B <= 0) continue;
    const int A = a * a - iy * iy;
    const int x0 = csqrt_d(A);
    int x1 = csqrt_d(B); if (x1 > cb + 1) x1 = cb + 1;
    if (x1 <= x0) continue;
    int off = abase[a] + rs[pid];
    const int ay = (iy >= 0) ? iy : -iy;
    const uint32_t hs = ((uint32_t)a << 16) | ((uint32_t)(iy + 32) << 8);
    if (x0 == 0) {
      for (int dx = -(x1 - 1); dx <= x1 - 1; ++dx) {
        const int adx = (dx >= 0) ? dx : -dx;
        dst[off++] = ((uint32_t)(ay + adx) << 24) | hs | (uint32_t)(dx + 32);
      }
    } else {
      for (int dx = -(x1 - 1); dx <= -x0; ++dx)
        dst[off++] = ((uint32_t)(ay - dx) << 24) | hs | (uint32_t)(dx + 32);
      for (int dx = x0; dx <= x1 - 1; ++dx)
        dst[off++] = ((uint32_t)(ay + dx) << 24) | hs | (uint32_t)(dx + 32);
    }
  }
  __syncthreads();
  if (tid == 0) {
    const int total = abase[amax + 1];
    // dummy: s=a=200 -> tail/rcp contributions exactly ~0; forces all-rcp
    // (exact) zones in its pair; gather lands in-bounds at (cb,cb).
    const uint32_t dummy = (200u << 24) | (200u << 16) |
                           ((uint32_t)(cb + 32) << 8) | (uint32_t)(cb + 32);
    for (int q = total; q < tab.ecnt[ci]; ++q) dst[q] = dummy;
  }
  __syncthreads();
  // per-pair meta: amin | amax<<8 | smin<<16 | smax<<24
  uint32_t* meta = ws + tab.moff[ci];
  const int npairs = tab.ecnt[ci] >> 7;
  for (int p = tid; p < npairs; p += 256) {
    int smin = 255, smax = 0, amin = 255, amx = 0;
    for (int q = 0; q < 128; ++q) {
      const uint32_t e = dst[p * 128 + q];
      const int s = (int)(e >> 24), aa = (int)((e >> 16) & 255);
      if (s < smin) smin = s; if (s > smax) smax = s;
      if (aa < amin) amin = aa; if (aa > amx) amx = aa;
    }
    meta[p] = (uint32_t)amin | ((uint32_t)amx << 8) |
              ((uint32_t)smin << 16) | ((uint32_t)smax << 24);
  }
}

// ------------------- direct path, kidx<=6 (round-6 code, runtime R) -------------------
template<int MAXR>
__device__ __forceinline__ void subwave_path(
    const float* __restrict__ xb, float (*s_red)[80],
    int k, int c, int nw, int k2, int R, float invk2, float rcpk,
    int pstart, int pend, int ch, int lpl, int wid, int lane) {
  const int LP = 1 << lpl;
  const int grp = lane >> lpl;
  const int l0 = lane & (LP - 1);
  const int gpw = 64 >> lpl;
  const int conc = gpw << 2;
  const int rounds = (ch + conc - 1) / conc;

  for (int it = 0; it < rounds; ++it) {
    const int patch = pstart + it * conc + wid * gpw + grp;
    float av[2][MAXR];
#pragma unroll
    for (int m = 0; m < 2; ++m)
#pragma unroll
      for (int r = 0; r < MAXR; ++r) av[m][r] = 0.0f;

    if (patch < pend) {
      const int ph = patch / nw, pw = patch - ph * nw;
      const float* pb = xb + (ph * k) * 224 + pw * k;
      const float center = pb[c * 224 + c];
      for (int p = l0; p < k2; p += LP) {
        const int i = (int)(((float)p + 0.5f) * rcpk);
        const int j = p - i * k;
        const float dy = fabsf((float)(i - c));
        const float dx = fabsf((float)(j - c));
        const float di = fabsf(pb[i * 224 + j] - center);
        const float dman = dy + dx + di;
        const float deuc = sqrtf(dy * dy + dx * dx + di * di);
        float Ee = __builtin_amdgcn_exp2f(L2E4f * (deuc - 1.0f));
        float Em = __builtin_amdgcn_exp2f(L2E4f * (dman - 1.0f));
#pragma unroll
        for (int r = 0; r < MAXR; ++r) {
          if (r < R) {
            av[0][r] += __builtin_amdgcn_rcpf(1.0f + Ee);
            av[1][r] += __builtin_amdgcn_rcpf(1.0f + Em);
            Ee *= QE4f; Em *= QE4f;
          }
        }
      }
    }
#pragma unroll
    for (int m = 0; m < 2; ++m)
#pragma unroll
      for (int r = 0; r < MAXR; ++r) {
        if (r < R) {
          float t = av[m][r];
          for (int off = LP >> 1; off > 0; off >>= 1) t += __shfl_xor(t, off, 64);
          float n = t * invk2;
          float nn = n * n;
          for (int off = LP; off < 64; off <<= 1) {
            n += __shfl_xor(n, off, 64);
            nn += __shfl_xor(nn, off, 64);
          }
          if (lane == 0) {
            s_red[wid][m * 40 + r * 2] += n;
            s_red[wid][m * 40 + r * 2 + 1] += nn;
          }
        }
      }
  }
}

// ------------------- merged ring-list pass (r12 zone body), strided -------------------
__device__ __forceinline__ void list_pass_merged(
    const uint32_t* __restrict__ lst, const uint32_t* __restrict__ meta, int pairs,
    int c0, int stride,
    const float* __restrict__ pb, float center, int c, int R,
    float (&av)[2][20], int lane) {
  int it = c0;
  if (it >= pairs) return;
  uint32_t e0 = lst[(2 * it) * 64 + lane], e1 = lst[(2 * it + 1) * 64 + lane];
  float px0 = pb[eaddr(e0, c)], px1 = pb[eaddr(e1, c)];
  uint32_t mv = meta[it];
  uint32_t f0 = e0, f1 = e1; float qx0 = px0, qx1 = px1; uint32_t mvn = mv;
  const int it1 = it + stride;
  if (it1 < pairs) {
    f0 = lst[(2 * it1) * 64 + lane]; f1 = lst[(2 * it1 + 1) * 64 + lane];
    qx0 = pb[eaddr(f0, c)]; qx1 = pb[eaddr(f1, c)];
    mvn = meta[it1];
  }
  while (it < pairs) {
    const uint32_t ce0 = e0, ce1 = e1, cmv = mv;
    const float cp0 = px0, cp1 = px1;
    // rotate pipeline; prefetch pair it + 2*stride
    e0 = f0; e1 = f1; px0 = qx0; px1 = qx1; mv = mvn;
    const int itp = it + 2 * stride;
    if (itp < pairs) {
      f0 = lst[(2 * itp) * 64 + lane];
      f1 = lst[(2 * itp + 1) * 64 + lane];
      qx0 = pb[eaddr(f0, c)];
      qx1 = pb[eaddr(f1, c)];
      mvn = meta[itp];
    }
    // ---- compute on current pair ----
    const int dx0 = (int)(ce0 & 255) - 32, iy0 = (int)((ce0 >> 8) & 255) - 32;
    const int dx1 = (int)(ce1 & 255) - 32, iy1 = (int)((ce1 >> 8) & 255) - 32;
    const float s0f = (float)(int)(ce0 >> 24), s1f = (float)(int)(ce1 >> 24);
    const int ms = __builtin_amdgcn_readfirstlane((int)cmv);
    const int alo = ms & 255, ahi = (ms >> 8) & 255;
    const int slo = (ms >> 16) & 255, shi = (ms >> 24) & 255;
    const float di0 = fabsf(cp0 - center), di1 = fabsf(cp1 - center);
    const float dm0 = s0f + di0, dm1 = s1f + di1;
    const float de0 = sqrtf(fmaf(di0, di0, (float)(iy0 * iy0 + dx0 * dx0)));
    const float de1 = sqrtf(fmaf(di1, di1, (float)(iy1 * iy1 + dx1 * dx1)));
    const float gm0 = __builtin_amdgcn_exp2f(-L2E4f * dm0);
    const float gm1 = __builtin_amdgcn_exp2f(-L2E4f * dm1);
    const float ge0 = __builtin_amdgcn_exp2f(-L2E4f * de0);
    const float ge1 = __builtin_amdgcn_exp2f(-L2E4f * de1);
    const float gms = gm0 + gm1, ges = ge0 + ge1;
    const int rloM = (slo - 1 > 1) ? slo - 1 : 1;
    const int rloE = (alo - 1 > 1) ? alo - 1 : 1;
    float EM0 = __builtin_amdgcn_exp2f(L2E4f * (dm0 - (float)rloM));
    float EM1 = __builtin_amdgcn_exp2f(L2E4f * (dm1 - (float)rloM));
    float EE0 = __builtin_amdgcn_exp2f(L2E4f * (de0 - (float)rloE));
    float EE1 = __builtin_amdgcn_exp2f(L2E4f * (de1 - (float)rloE));
    const float hms = (shi + 3 <= R)
        ? (__builtin_amdgcn_rcpf(gm0) + __builtin_amdgcn_rcpf(gm1)) : 0.0f;
    const float hes = (ahi + 3 <= R)
        ? (__builtin_amdgcn_rcpf(ge0) + __builtin_amdgcn_rcpf(ge1)) : 0.0f;
#pragma unroll
    for (int r = 1; r <= 20; ++r) {
      if (r <= R) {
        if (r < rloE) {
          av[0][r - 1] = fmaf(PRt[r], ges, av[0][r - 1]);
        } else if (r <= ahi + 2) {
          av[0][r - 1] += __builtin_amdgcn_rcpf(1.0f + EE0)
                        + __builtin_amdgcn_rcpf(1.0f + EE1);
          EE0 *= QE4f; EE1 *= QE4f;
        } else {
          av[0][r - 1] += fmaf(hes, -QRt[r], 2.0f);
        }
        if (r < rloM) {
          av[1][r - 1] = fmaf(PRt[r], gms, av[1][r - 1]);
        } else if (r <= shi + 2) {
          av[1][r - 1] += __builtin_amdgcn_rcpf(1.0f + EM0)
                        + __builtin_amdgcn_rcpf(1.0f + EM1);
          EM0 *= QE4f; EM1 *= QE4f;
        } else {
          av[1][r - 1] += fmaf(hms, -QRt[r], 2.0f);
        }
      }
    }
    it += stride;
  }
}

__global__ __launch_bounds__(256) void fractal_main(const float* __restrict__ x,
                                                    float* __restrict__ ws, Tabs tab) {
  const int g = (int)blockIdx.x;
  const int b = (int)blockIdx.y;
  int seq = 0;
  while (g >= tab.gpre[seq + 1]) ++seq;
  const int kidx = tab.kofseq[seq];
  const int lc = g - tab.gpre[seq];
  const int k = 3 + 2 * kidx, c = k >> 1, nw = 224 / k;
  const int P = nw * nw, k2 = k * k;
  int R = kidx + 1; if (R < 2) R = 2; if (R > 20) R = 20;
  const float invk2 = 1.0f / (float)k2;
  const float rcpk = 1.0f / (float)k;
  const float* xb = x + b * 50176;
  const int tid = (int)threadIdx.x, wid = tid >> 6, lane = tid & 63;
  const int ch = tab.CH[kidx];
  const int pstart = lc * ch;
  int pend = pstart + ch; if (pend > P) pend = P;

  __shared__ float s_red[4][80];
  __shared__ float s_acc[80];
  for (int t = tid; t < 320; t += 256) (&s_red[0][0])[t] = 0.0f;
  if (tid < 80) s_acc[tid] = 0.0f;
  __syncthreads();

  bool blockmode = false;

  if (kidx <= 6) {
    const int lpl = (kidx <= 2) ? 0 : 2;
    subwave_path<8>(xb, s_red, k, c, nw, k2, R, invk2, rcpk, pstart, pend, ch, lpl, wid, lane);
  } else {
    const int ci = (kidx + 1 <= 24) ? (kidx - 7) : 17;
    const uint32_t* wsu = (const uint32_t*)ws;
    const uint32_t* el = wsu + tab.eoff[ci];
    const uint32_t* meta = wsu + tab.moff[ci];
    const int pairs = tab.ecnt[ci] >> 7;

    if (P <= 16) {
      // -------- block-mode: 4 waves cooperate on each patch (pairs split by wid) --------
      blockmode = true;
      for (int patch = pstart; patch < pend; ++patch) {
        const int ph = patch / nw, pw = patch - ph * nw;
        const float* pb = xb + (ph * k) * 224 + pw * k;
        const float center = pb[c * 224 + c];
        float av[2][20];
#pragma unroll
        for (int m = 0; m < 2; ++m)
#pragma unroll
          for (int r = 0; r < 20; ++r) av[m][r] = 0.0f;

        list_pass_merged(el, meta, pairs, wid, 4, pb, center, c, R, av, lane);

#pragma unroll
        for (int m = 0; m < 2; ++m)
#pragma unroll
          for (int r = 0; r < 20; ++r) {
            if (r < R) {
              const float tot = wred64(av[m][r]);
              if (lane == 0) s_red[wid][m * 40 + r * 2] = tot;   // raw partial
            }
          }
        __syncthreads();
        if (tid < 40) {
          const int mm = tid / 20, rr = tid - 20 * (tid / 20);
          if (rr < R) {
            const int slot = mm * 40 + rr * 2;
            const float tot = s_red[0][slot] + s_red[1][slot] +
                              s_red[2][slot] + s_red[3][slot];
            const float n = tot * invk2;
            s_acc[slot] += n;
            s_acc[slot + 1] += n * n;
          }
        }
        __syncthreads();   // protect s_red reuse next patch
      }
    } else {
      // -------- wave-mode (r12): one patch per wave --------
      for (int patch = pstart + wid; patch < pend; patch += 4) {
        const int ph = patch / nw, pw = patch - ph * nw;
        const float* pb = xb + (ph * k) * 224 + pw * k;
        const float center = pb[c * 224 + c];
        float av[2][20];
#pragma unroll
        for (int m = 0; m < 2; ++m)
#pragma unroll
          for (int r = 0; r < 20; ++r) av[m][r] = 0.0f;

        list_pass_merged(el, meta, pairs, 0, 1, pb, center, c, R, av, lane);

#pragma unroll
        for (int m = 0; m < 2; ++m)
#pragma unroll
          for (int r = 0; r < 20; ++r) {
            if (r < R) {
              const float tot = wred64(av[m][r]);
              if (lane == 0) {
                const float n = tot * invk2;
                s_red[wid][m * 40 + r * 2] += n;
                s_red[wid][m * 40 + r * 2 + 1] += n * n;
              }
            }
          }
      }
    }
  }

  __syncthreads();
  float* dst = ws + tab.pbase + ((size_t)b * tab.GT + g) * 80;
  if (tid < 80)
    dst[tid] = blockmode ? s_acc[tid]
                         : s_red[0][tid] + s_red[1][tid] + s_red[2][tid] + s_red[3][tid];
}

__global__ __launch_bounds__(64) void fractal_final(const float* __restrict__ ws,
                                                    float* __restrict__ out, Tabs tab) {
  const int kb = (int)blockIdx.x;        // 800 blocks: (kidx, b)
  const int kidx = kb >> 4, b = kb & 15;
  int seq = 0;
  for (int j = 0; j < 50; ++j) if (tab.kofseq[j] == kidx) seq = j;
  const int g0 = tab.gpre[seq], g1 = tab.gpre[seq + 1];
  const int k = 3 + 2 * kidx, c = k >> 1, nw = 224 / k;
  const int P = nw * nw, k2 = k * k;
  int R = kidx + 1; if (R < 2) R = 2; if (R > 20) R = 20;
  const float invP = 1.0f / (float)P;
  const int lane = (int)threadIdx.x;

  float lmean = 0.0f;
  for (int r0 = 0; r0 < 20; ++r0) if (r0 < R) lmean += LXT[r0];
  lmean /= (float)R;
  float sxx = 0.0f;
  for (int r0 = 0; r0 < 20; ++r0)
    if (r0 < R) { const float xc = LXT[r0] - lmean; sxx += xc * xc; }

  __shared__ float s_lac[64], s_sxy[64];
  float lact = 0.0f, sxyt = 0.0f;
  if (lane < 60) {
    const int mo = lane / 20;            // 0=cheb, 1=euc, 2=man
    const int r0 = lane % 20, rr = r0 + 1;
    if (rr <= R) {
      float m1, m2;
      if (mo == 0) {
        int s0 = rr - 3; if (s0 > c) s0 = c;
        float acc = (s0 >= 0) ? (1.0f + 4.0f * (float)(s0 * (s0 + 1))) : 0.0f;
        int slo = rr - 2; if (slo < 0) slo = 0;
        int shi = rr + 3; if (shi > c) shi = c;
        for (int s = slo; s <= shi; ++s) {
          const float w = (s == 0) ? 1.0f : 8.0f * (float)s;
          acc += w * __builtin_amdgcn_rcpf(
                   1.0f + __builtin_amdgcn_exp2f(L2E4f * (float)(s - rr)));
        }
        m1 = acc / (float)k2;
        m2 = m1 * m1;
      } else {
        const int mws = mo - 1;          // ws: 0=euc, 1=man
        float sn = 0.0f, sn2 = 0.0f;
        for (int gg = g0; gg < g1; ++gg) {
          const float* p = ws + tab.pbase + ((size_t)b * tab.GT + gg) * 80 + mws * 40 + r0 * 2;
          sn += p[0]; sn2 += p[1];
        }
        m1 = sn * invP; m2 = sn2 * invP;
      }
      lact = m2 / (m1 * m1 + 1e-8f);
      sxyt = __log2f(m1 + 1e-8f) * 0.69314718f * (LXT[r0] - lmean);
    }
  }
  s_lac[lane] = lact; s_sxy[lane] = sxyt;
  __syncthreads();
  if (lane < 3) {
    float L = 0.0f, S = 0.0f;
    for (int r0 = 0; r0 < 20; ++r0) { L += s_lac[lane * 20 + r0]; S += s_sxy[lane * 20 + r0]; }
    out[b * 300 + kidx * 3 + lane] = L / (float)R;          // cols 0..49: lacunarity
    out[b * 300 + (50 + kidx) * 3 + lane] = -S / sxx;       // cols 50..99: fractal dim
  }
}

static inline int csqrt_h(int v) {
  if (v <= 0) return 0;
  int x = 0;
  while (x * x < v) ++x;
  return x;
}

extern "C" void kernel_launch(void* const* d_in, const int* in_sizes, int n_in,
                              void* d_out, int out_size, void* d_ws, size_t ws_size,
                              hipStream_t stream) {
  Tabs tab;

  // ---- merged list layout (host replicates disc counting; pad to 128) ----
  int lw = 0;
  for (int ci = 0; ci < 18; ++ci) {
    const int c_eff = 8 + ci;
    const int cb = (c_eff < 24) ? c_eff : 24;
    const int Rcl = (c_eff < 20) ? c_eff : 20;
    const int amax = (Rcl + 4 < 24) ? Rcl + 4 : 24;
    int ec = 0;
    for (int a = 0; a <= amax; ++a)
      for (int iy = -cb; iy <= cb; ++iy) {
        const int B = (a + 1) * (a + 1) - iy * iy;
        if (B <= 0) continue;
        const int A = a * a - iy * iy;
        const int x0 = csqrt_h(A);
        int x1 = csqrt_h(B); if (x1 > cb + 1) x1 = cb + 1;
        if (x1 > x0) ec += (x0 == 0) ? (2 * x1 - 1) : 2 * (x1 - x0);
      }
    const int ecp = (ec + 127) & ~127;
    const int mw = ecp >> 7;
    tab.eoff[ci] = lw; tab.ecnt[ci] = ecp; lw += ecp;
    tab.moff[ci] = lw; tab.mcnt[ci] = mw;  lw += mw;
  }
  tab.pbase = lw;
  const long budget = (long)ws_size - 4L * lw;

  // ---- chunker ----
  long T = 5000;
  int G_[50], CH_[50];
  long bc[50];
  for (int tries = 0; tries < 8; ++tries) {
    long GTl = 0;
    for (int i = 0; i < 50; ++i) {
      const int k = 3 + 2 * i, nw = 224 / k, P = nw * nw, k2 = k * k;
      int R = i + 1; if (R < 2) R = 2; if (R > 20) R = 20;
      if (i <= 6) {
        const int lpl = (i <= 2) ? 0 : 2;
        const int LP = 1 << lpl, conc = 256 >> lpl;
        const long rc = (long)((k2 + LP - 1) / LP) * 2L * (12L * R + 8L);
        long np = T / rc; if (np < 1) np = 1;
        long cht = np * conc; if (cht > P) cht = P;
        int G = (int)(((long)P + cht - 1) / cht);
        int ch = (P + G - 1) / G; G = (P + ch - 1) / ch;
        G_[i] = G; CH_[i] = ch;
        bc[i] = (long)((ch + conc - 1) / conc) * rc;
      } else {
        const int ci = (i + 1 <= 24) ? (i - 7) : 17;
        const long pairsL = (long)(tab.ecnt[ci] >> 7);
        const long ppc = pairsL * 560 + 1100;           // wave-cyc per patch (wave-mode)
        if (P <= 16) {
          // block-mode: 4 waves split a patch
          const long ppw = ppc / 4 + 300;
          long chL = T / ppw; if (chL < 1) chL = 1; if (chL > P) chL = P;
          int G = (int)(((long)P + chL - 1) / chL);
          int ch = (P + G - 1) / G; G = (P + ch - 1) / ch;
          G_[i] = G; CH_[i] = ch;
          bc[i] = (long)ch * ppw;
        } else {
          long nppb = T / ppc; if (nppb < 4) nppb = 4;
          int cht = (int)(((nppb + 3) / 4) * 4); if (cht > P) cht = P;
          int G = (P + cht - 1) / cht;
          int ch = (P + G - 1) / G; G = (P + ch - 1) / ch;
          G_[i] = G; CH_[i] = ch;
          bc[i] = (long)((ch + 3) / 4) * ppc;
        }
      }
      GTl += G_[i];
    }
    if (16L * GTl * 80L * 4L <= budget || tries == 7) break;
    T *= 2;
  }
  // heaviest blocks first
  int ord[50];
  for (int i = 0; i < 50; ++i) ord[i] = i;
  for (int a = 1; a < 50; ++a) {
    const int key = ord[a]; const long kw = bc[key];
    int bp = a - 1;
    while (bp >= 0 && bc[ord[bp]] < kw) { ord[bp + 1] = ord[bp]; --bp; }
    ord[bp + 1] = key;
  }
  tab.gpre[0] = 0;
  for (int j = 0; j < 50; ++j) {
    tab.kofseq[j] = ord[j];
    tab.gpre[j + 1] = tab.gpre[j] + G_[ord[j]];
  }
  for (int i = 0; i < 50; ++i) tab.CH[i] = CH_[i];
  tab.GT = tab.gpre[50];

  const float* x = (const float*)d_in[0];
  build_lists<<<18, 256, 0, stream>>>((uint32_t*)d_ws, tab);
  fractal_main<<<dim3(tab.GT, 16), 256, 0, stream>>>(x, (float*)d_ws, tab);
  fractal_final<<<800, 64, 0, stream>>>((const float*)d_ws, (float*)d_out, tab);
}

// Round 15
// 176.981 us; speedup vs baseline: 1.2273x; 1.2273x over previous
//
#include <hip/hip_runtime.h>
#include <stdint.h>

// FractalImage: B=16, 224x224, k=3+2*kidx, kidx in [0,50), 3 metrics.
// Chebyshev: data-independent (x in [0,1)) -> analytic in finalize.
// kidx<=6: direct per-pixel r-loop (runtime R<=7), exp-recurrence sigmoid.
// kidx>=7: ring-sorted pixel lists (Man: diamond rings s; Euc: annuli a).
//   Zone math per 128-entry chunk pair (wave-uniform slo/shi, sorted list):
//     r <= slo-2  : sigma ~= e^{4r} * e^{-4d}      (1 fma, summed pair)
//     r <= shi+2  : sigma  = 1/(1+E), two independent E-chains
//     r >  shi+2  : sigma ~= 1 - e^{4d} * e^{-4r}  (1 fma, summed pair)
//   == round 11 EXACTLY (best measured: 183.65us total, absmax 0.0, VGPR 48)
//   plus __launch_bounds__(256,8) occupancy hint (cap 64 VGPR >= current 48).
//   Probes r10-r14 (dual-patch, trans-cut, merged-list, branch-free chain,
//   block-mode) all null/negative -> this structure is the validated optimum.

#define L2E4f 5.770780163555854f    // 4*log2(e)
#define QE4f  0.0183156388887342f   // e^-4

struct Tabs {
  int gpre[51];
  int CH[50];
  int kofseq[50];
  int GT;
  int eoff[18], ecnt[18];   // euclid list offset (u32 words) / padded count (x128)
  int moff[18], mcnt[18];   // manhattan
  int pbase;                // partial-slot base (float index into ws)
};

__device__ __constant__ float LXT[20] = {
  0.0f, 0.69314718f, 1.09861229f, 1.38629436f, 1.60943791f,
  1.79175947f, 1.94591015f, 2.07944154f, 2.19722458f, 2.30258509f,
  2.39789527f, 2.48490665f, 2.56494936f, 2.63905733f, 2.70805020f,
  2.77258872f, 2.83321334f, 2.89037176f, 2.94443898f, 2.99573227f};

// e^{4r} and e^{-4r}, r=0..20 (static-indexed -> immediates)
constexpr float PRt[21] = {1.0f,
  5.45981500e1f, 2.98095799e3f, 1.62754791e5f, 8.88611052e6f, 4.85165195e8f,
  2.64891221e10f, 1.44625706e12f, 7.89629602e13f, 4.31123155e15f, 2.35385267e17f,
  1.28516001e19f, 7.01673591e20f, 3.83100800e22f, 2.09165950e24f, 1.14200739e26f,
  6.23514908e27f, 3.40427605e29f, 1.85867175e31f, 1.01480039e33f, 5.54062238e34f};
constexpr float QRt[21] = {1.0f,
  1.83156389e-2f, 3.35462628e-4f, 6.14421235e-6f, 1.12535175e-7f, 2.06115362e-9f,
  3.77513454e-11f, 6.91440011e-13f, 1.26641655e-14f, 2.31952283e-16f, 4.24835426e-18f,
  7.78113224e-20f, 1.42516408e-21f, 2.61027907e-23f, 4.78089288e-25f, 8.75651076e-27f,
  1.60381089e-28f, 2.93748211e-30f, 5.38018616e-32f, 9.85415469e-34f, 1.80485139e-35f};

__device__ __forceinline__ float wred64(float v) {
#pragma unroll
  for (int off = 32; off > 0; off >>= 1) v += __shfl_xor(v, off, 64);
  return v;
}

__device__ __forceinline__ int csqrt_d(int v) {   // smallest x>=0 with x*x>=v
  if (v <= 0) return 0;
  int x = (int)sqrtf((float)v);
  while (x * x < v) ++x;
  while (x > 0 && (x - 1) * (x - 1) >= v) --x;
  return x;
}

// ------------------- list builder (36 blocks: 18 classes x 2 metrics) -------------------
__global__ __launch_bounds__(256) void build_lists(uint32_t* ws, Tabs tab) {
  const int ci = (int)blockIdx.x >> 1;
  const int metric = (int)blockIdx.x & 1;     // 0=euc, 1=man
  const int c_eff = 8 + ci;
  const int cb = (c_eff < 24) ? c_eff : 24;
  const int Rcl = (c_eff < 20) ? c_eff : 20;
  const int tid = (int)threadIdx.x;

  if (metric == 1) {
    const int t1 = (Rcl + 4 < 24) ? Rcl + 4 : 24;
    const int smax = (t1 < 2 * cb) ? t1 : 2 * cb;
    uint32_t* dst = ws + tab.moff[ci];
    for (int s = tid; s <= smax; s += 256) {
      int off = 0;
      for (int s2 = 0; s2 < s; ++s2)
        off += (s2 == 0) ? 1 : ((s2 <= cb) ? 4 * s2 : ((s2 <= 2 * cb) ? 4 * (2 * cb - s2 + 1) : 0));
      const int lim = (s < cb) ? s : cb;
      for (int iy = -lim; iy <= lim; ++iy) {
        const int v = s - ((iy >= 0) ? iy : -iy);
        if (v > cb) continue;
        const uint32_t hs = ((uint32_t)s << 16) | ((uint32_t)(iy + 32) << 8);
        if (v == 0) dst[off++] = hs | 32u;
        else { dst[off++] = hs | (uint32_t)(-v + 32); dst[off++] = hs | (uint32_t)(v + 32); }
      }
    }
    if (tid == 0) {
      int total = 0;
      for (int s = 0; s <= smax; ++s)
        total += (s == 0) ? 1 : ((s <= cb) ? 4 * s : ((s <= 2 * cb) ? 4 * (2 * cb - s + 1) : 0));
      const uint32_t dummy = (40u << 16) | ((uint32_t)(cb + 32) << 8) | (uint32_t)(cb + 32);
      for (int q = total; q < tab.mcnt[ci]; ++q) dst[q] = dummy;
    }
  } else {
    const int amax = (Rcl + 4 < 24) ? Rcl + 4 : 24;
    const int W = 2 * cb + 1;
    __shared__ int rs[25 * 49];
    __shared__ int abase[26];
    uint32_t* dst = ws + tab.eoff[ci];
    for (int pid = tid; pid < (amax + 1) * W; pid += 256) {
      const int a = pid / W, iy = pid % W - cb;
      const int B = (a + 1) * (a + 1) - iy * iy;
      int len = 0;
      if (B > 0) {
        const int A = a * a - iy * iy;
        const int x0 = csqrt_d(A);
        int x1 = csqrt_d(B); if (x1 > cb + 1) x1 = cb + 1;
        if (x1 > x0) len = (x0 == 0) ? (2 * x1 - 1) : 2 * (x1 - x0);
      }
      rs[pid] = len;
    }
    __syncthreads();
    if (tid <= amax) {
      int acc = 0;
      for (int iyi = 0; iyi < W; ++iyi) { const int L = rs[tid * W + iyi]; rs[tid * W + iyi] = acc; acc += L; }
      abase[tid + 1] = acc;
    }
    __syncthreads();
    if (tid == 0) { abase[0] = 0; for (int a = 1; a <= amax + 1; ++a) abase[a] += abase[a - 1]; }
    __syncthreads();
    for (int pid = tid; pid < (amax + 1) * W; pid += 256) {
      const int a = pid / W, iy = pid % W - cb;
      const int B = (a + 1) * (a + 1) - iy * iy;
      if (B <= 0) continue;
      const int A = a * a - iy * iy;
      const int x0 = csqrt_d(A);
      int x1 = csqrt_d(B); if (x1 > cb + 1) x1 = cb + 1;
      if (x1 <= x0) continue;
      int off = abase[a] + rs[pid];
      const uint32_t hs = ((uint32_t)a << 16) | ((uint32_t)(iy + 32) << 8);
      if (x0 == 0) {
        for (int dx = -(x1 - 1); dx <= x1 - 1; ++dx) dst[off++] = hs | (uint32_t)(dx + 32);
      } else {
        for (int dx = -(x1 - 1); dx <= -x0; ++dx) dst[off++] = hs | (uint32_t)(dx + 32);
        for (int dx = x0; dx <= x1 - 1; ++dx)     dst[off++] = hs | (uint32_t)(dx + 32);
      }
    }
    __syncthreads();
    if (tid == 0) {
      const int total = abase[amax + 1];
      const uint32_t dummy = (40u << 16) | ((uint32_t)(cb + 32) << 8) | (uint32_t)(cb + 32);
      for (int q = total; q < tab.ecnt[ci]; ++q) dst[q] = dummy;
    }
  }
}

// ------------------- direct path, kidx<=6 (round-6 code, runtime R) -------------------
template<int MAXR>
__device__ __forceinline__ void subwave_path(
    const float* __restrict__ xb, float (*s_red)[80],
    int k, int c, int nw, int k2, int R, float invk2, float rcpk,
    int pstart, int pend, int ch, int lpl, int wid, int lane) {
  const int LP = 1 << lpl;
  const int grp = lane >> lpl;
  const int l0 = lane & (LP - 1);
  const int gpw = 64 >> lpl;
  const int conc = gpw << 2;
  const int rounds = (ch + conc - 1) / conc;

  for (int it = 0; it < rounds; ++it) {
    const int patch = pstart + it * conc + wid * gpw + grp;
    float av[2][MAXR];
#pragma unroll
    for (int m = 0; m < 2; ++m)
#pragma unroll
      for (int r = 0; r < MAXR; ++r) av[m][r] = 0.0f;

    if (patch < pend) {
      const int ph = patch / nw, pw = patch - ph * nw;
      const float* pb = xb + (ph * k) * 224 + pw * k;
      const float center = pb[c * 224 + c];
      for (int p = l0; p < k2; p += LP) {
        const int i = (int)(((float)p + 0.5f) * rcpk);
        const int j = p - i * k;
        const float dy = fabsf((float)(i - c));
        const float dx = fabsf((float)(j - c));
        const float di = fabsf(pb[i * 224 + j] - center);
        const float dman = dy + dx + di;
        const float deuc = sqrtf(dy * dy + dx * dx + di * di);
        float Ee = __builtin_amdgcn_exp2f(L2E4f * (deuc - 1.0f));
        float Em = __builtin_amdgcn_exp2f(L2E4f * (dman - 1.0f));
#pragma unroll
        for (int r = 0; r < MAXR; ++r) {
          if (r < R) {
            av[0][r] += __builtin_amdgcn_rcpf(1.0f + Ee);
            av[1][r] += __builtin_amdgcn_rcpf(1.0f + Em);
            Ee *= QE4f; Em *= QE4f;
          }
        }
      }
    }
#pragma unroll
    for (int m = 0; m < 2; ++m)
#pragma unroll
      for (int r = 0; r < MAXR; ++r) {
        if (r < R) {
          float t = av[m][r];
          for (int off = LP >> 1; off > 0; off >>= 1) t += __shfl_xor(t, off, 64);
          float n = t * invk2;
          float nn = n * n;
          for (int off = LP; off < 64; off <<= 1) {
            n += __shfl_xor(n, off, 64);
            nn += __shfl_xor(nn, off, 64);
          }
          if (lane == 0) {
            s_red[wid][m * 40 + r * 2] += n;
            s_red[wid][m * 40 + r * 2 + 1] += nn;
          }
        }
      }
  }
}

// ------------------- ring-list pass: paired chunks, runtime R, narrow zones -------------------
template<int METRIC>
__device__ __forceinline__ void list_pass_pair(
    const uint32_t* __restrict__ lst, int pairs,
    const float* __restrict__ pb, float center,
    int c, int R, float (&av)[2][20], int lane) {
  uint32_t e0 = lst[lane];
  uint32_t e1 = lst[64 + lane];
  for (int it = 0; it < pairs; ++it) {
    // issue both gathers for the current pair immediately
    const int iy0 = (int)((e0 >> 8) & 255) - 32, dx0 = (int)(e0 & 255) - 32;
    const int iy1 = (int)((e1 >> 8) & 255) - 32, dx1 = (int)(e1 & 255) - 32;
    const float px0 = pb[(c + iy0) * 224 + (c + dx0)];
    const float px1 = pb[(c + iy1) * 224 + (c + dx1)];
    const int s0 = (int)(e0 >> 16), s1 = (int)(e1 >> 16);
    const int slo = __builtin_amdgcn_readfirstlane(s0);          // min of pair (sorted)
    const int shi = __builtin_amdgcn_readfirstlane(__shfl(s1, 63));  // max of pair
    // prefetch next pair's entries
    uint32_t en0 = 0u, en1 = 0u;
    if (it + 1 < pairs) {
      en0 = lst[(2 * it + 2) * 64 + lane];
      en1 = lst[(2 * it + 3) * 64 + lane];
    }

    const int rlo = (slo - 1 > 1) ? slo - 1 : 1;                 // narrowed (r10-validated)
    const float di0 = fabsf(px0 - center);
    const float di1 = fabsf(px1 - center);
    float d0, d1;
    if (METRIC == 1) {
      d0 = (float)s0 + di0;
      d1 = (float)s1 + di1;
    } else {
      d0 = sqrtf(fmaf(di0, di0, (float)(iy0 * iy0 + dx0 * dx0)));
      d1 = sqrtf(fmaf(di1, di1, (float)(iy1 * iy1 + dx1 * dx1)));
    }
    const float g0 = __builtin_amdgcn_exp2f(-L2E4f * d0);
    const float g1 = __builtin_amdgcn_exp2f(-L2E4f * d1);
    const float gs = g0 + g1;                                     // tail: 1 fma / r
    float E0 = __builtin_amdgcn_exp2f(L2E4f * (d0 - (float)rlo)); // two independent chains
    float E1 = __builtin_amdgcn_exp2f(L2E4f * (d1 - (float)rlo));
    const bool haveones = (shi + 3 <= R);                         // narrowed
    const float hs = haveones
        ? (__builtin_amdgcn_rcpf(g0) + __builtin_amdgcn_rcpf(g1)) : 0.0f;
#pragma unroll
    for (int r = 1; r <= 20; ++r) {
      if (r <= R) {
        if (r < rlo) {
          av[METRIC][r - 1] = fmaf(PRt[r], gs, av[METRIC][r - 1]);
        } else if (r <= shi + 2) {                                // narrowed
          av[METRIC][r - 1] += __builtin_amdgcn_rcpf(1.0f + E0)
                             + __builtin_amdgcn_rcpf(1.0f + E1);
          E0 *= QE4f; E1 *= QE4f;
        } else {
          av[METRIC][r - 1] += fmaf(hs, -QRt[r], 2.0f);
        }
      }
    }
    e0 = en0; e1 = en1;
  }
}

__global__ __launch_bounds__(256, 8) void fractal_main(const float* __restrict__ x,
                                                       float* __restrict__ ws, Tabs tab) {
  const int g = (int)blockIdx.x;
  const int b = (int)blockIdx.y;
  int seq = 0;
  while (g >= tab.gpre[seq + 1]) ++seq;
  const int kidx = tab.kofseq[seq];
  const int lc = g - tab.gpre[seq];
  const int k = 3 + 2 * kidx, c = k >> 1, nw = 224 / k;
  const int P = nw * nw, k2 = k * k;
  int R = kidx + 1; if (R < 2) R = 2; if (R > 20) R = 20;
  const float invk2 = 1.0f / (float)k2;
  const float rcpk = 1.0f / (float)k;
  const float* xb = x + b * 50176;
  const int tid = (int)threadIdx.x, wid = tid >> 6, lane = tid & 63;
  const int ch = tab.CH[kidx];
  const int pstart = lc * ch;
  int pend = pstart + ch; if (pend > P) pend = P;

  __shared__ float s_red[4][80];
  for (int t = tid; t < 320; t += 256) (&s_red[0][0])[t] = 0.0f;
  __syncthreads();

  if (kidx <= 6) {
    const int lpl = (kidx <= 2) ? 0 : 2;
    subwave_path<8>(xb, s_red, k, c, nw, k2, R, invk2, rcpk, pstart, pend, ch, lpl, wid, lane);
  } else {
    const int ci = (kidx + 1 <= 24) ? (kidx - 7) : 17;
    const uint32_t* wsu = (const uint32_t*)ws;
    const uint32_t* el = wsu + tab.eoff[ci];
    const uint32_t* ml = wsu + tab.moff[ci];
    const int ep = tab.ecnt[ci] >> 7, mp = tab.mcnt[ci] >> 7;   // chunk PAIRS
    for (int patch = pstart + wid; patch < pend; patch += 4) {
      const int ph = patch / nw, pw = patch - ph * nw;
      const float* pb = xb + (ph * k) * 224 + pw * k;
      const float center = pb[c * 224 + c];
      float av[2][20];
#pragma unroll
      for (int m = 0; m < 2; ++m)
#pragma unroll
        for (int r = 0; r < 20; ++r) av[m][r] = 0.0f;

      list_pass_pair<0>(el, ep, pb, center, c, R, av, lane);
      list_pass_pair<1>(ml, mp, pb, center, c, R, av, lane);

#pragma unroll
      for (int m = 0; m < 2; ++m)
#pragma unroll
        for (int r = 0; r < 20; ++r) {
          if (r < R) {
            const float tot = wred64(av[m][r]);
            if (lane == 0) {
              const float n = tot * invk2;
              s_red[wid][m * 40 + r * 2] += n;
              s_red[wid][m * 40 + r * 2 + 1] += n * n;
            }
          }
        }
    }
  }

  __syncthreads();
  float* dst = ws + tab.pbase + ((size_t)b * tab.GT + g) * 80;
  if (tid < 80) dst[tid] = s_red[0][tid] + s_red[1][tid] + s_red[2][tid] + s_red[3][tid];
}

__global__ __launch_bounds__(64) void fractal_final(const float* __restrict__ ws,
                                                    float* __restrict__ out, Tabs tab) {
  const int kb = (int)blockIdx.x;        // 800 blocks: (kidx, b)
  const int kidx = kb >> 4, b = kb & 15;
  int seq = 0;
  for (int j = 0; j < 50; ++j) if (tab.kofseq[j] == kidx) seq = j;
  const int g0 = tab.gpre[seq], g1 = tab.gpre[seq + 1];
  const int k = 3 + 2 * kidx, c = k >> 1, nw = 224 / k;
  const int P = nw * nw, k2 = k * k;
  int R = kidx + 1; if (R < 2) R = 2; if (R > 20) R = 20;
  const float invP = 1.0f / (float)P;
  const int lane = (int)threadIdx.x;

  float lmean = 0.0f;
  for (int r0 = 0; r0 < 20; ++r0) if (r0 < R) lmean += LXT[r0];
  lmean /= (float)R;
  float sxx = 0.0f;
  for (int r0 = 0; r0 < 20; ++r0)
    if (r0 < R) { const float xc = LXT[r0] - lmean; sxx += xc * xc; }

  __shared__ float s_lac[64], s_sxy[64];
  float lact = 0.0f, sxyt = 0.0f;
  if (lane < 60) {
    const int mo = lane / 20;            // 0=cheb, 1=euc, 2=man
    const int r0 = lane % 20, rr = r0 + 1;
    if (rr <= R) {
      float m1, m2;
      if (mo == 0) {
        int s0 = rr - 3; if (s0 > c) s0 = c;
        float acc = (s0 >= 0) ? (1.0f + 4.0f * (float)(s0 * (s0 + 1))) : 0.0f;
        int slo = rr - 2; if (slo < 0) slo = 0;
        int shi = rr + 3; if (shi > c) shi = c;
        for (int s = slo; s <= shi; ++s) {
          const float w = (s == 0) ? 1.0f : 8.0f * (float)s;
          acc += w * __builtin_amdgcn_rcpf(
                   1.0f + __builtin_amdgcn_exp2f(L2E4f * (float)(s - rr)));
        }
        m1 = acc / (float)k2;
        m2 = m1 * m1;
      } else {
        const int mws = mo - 1;          // ws: 0=euc, 1=man
        float sn = 0.0f, sn2 = 0.0f;
        for (int gg = g0; gg < g1; ++gg) {
          const float* p = ws + tab.pbase + ((size_t)b * tab.GT + gg) * 80 + mws * 40 + r0 * 2;
          sn += p[0]; sn2 += p[1];
        }
        m1 = sn * invP; m2 = sn2 * invP;
      }
      lact = m2 / (m1 * m1 + 1e-8f);
      sxyt = logf(m1 + 1e-8f) * (LXT[r0] - lmean);
    }
  }
  s_lac[lane] = lact; s_sxy[lane] = sxyt;
  __syncthreads();
  if (lane < 3) {
    float L = 0.0f, S = 0.0f;
    for (int r0 = 0; r0 < 20; ++r0) { L += s_lac[lane * 20 + r0]; S += s_sxy[lane * 20 + r0]; }
    out[b * 300 + kidx * 3 + lane] = L / (float)R;          // cols 0..49: lacunarity
    out[b * 300 + (50 + kidx) * 3 + lane] = -S / sxx;       // cols 50..99: fractal dim
  }
}

static inline int csqrt_h(int v) {
  if (v <= 0) return 0;
  int x = 0;
  while (x * x < v) ++x;
  return x;
}

extern "C" void kernel_launch(void* const* d_in, const int* in_sizes, int n_in,
                              void* d_out, int out_size, void* d_ws, size_t ws_size,
                              hipStream_t stream) {
  Tabs tab;

  // ---- list layout (host replicates builder counting; pad to 128 = chunk pair) ----
  int lw = 0;
  for (int ci = 0; ci < 18; ++ci) {
    const int c_eff = 8 + ci;
    const int cb = (c_eff < 24) ? c_eff : 24;
    const int Rcl = (c_eff < 20) ? c_eff : 20;
    const int amax = (Rcl + 4 < 24) ? Rcl + 4 : 24;
    const int t1 = (Rcl + 4 < 24) ? Rcl + 4 : 24;
    const int smax = (t1 < 2 * cb) ? t1 : 2 * cb;
    int ec = 0;
    for (int a = 0; a <= amax; ++a)
      for (int iy = -cb; iy <= cb; ++iy) {
        const int B = (a + 1) * (a + 1) - iy * iy;
        if (B <= 0) continue;
        const int A = a * a - iy * iy;
        const int x0 = csqrt_h(A);
        int x1 = csqrt_h(B); if (x1 > cb + 1) x1 = cb + 1;
        if (x1 > x0) ec += (x0 == 0) ? (2 * x1 - 1) : 2 * (x1 - x0);
      }
    int mc = 0;
    for (int s = 0; s <= smax; ++s)
      mc += (s == 0) ? 1 : ((s <= cb) ? 4 * s : ((s <= 2 * cb) ? 4 * (2 * cb - s + 1) : 0));
    const int ecp = (ec + 127) & ~127;
    const int mcp = (mc + 127) & ~127;
    tab.eoff[ci] = lw; tab.ecnt[ci] = ecp; lw += ecp;
    tab.moff[ci] = lw; tab.mcnt[ci] = mcp; lw += mcp;
  }
  tab.pbase = lw;
  const long budget = (long)ws_size - 4L * lw;

  // ---- chunker (round-9 cost model, verbatim) ----
  long T = 10000;
  int G_[50], CH_[50];
  long bc[50];
  for (int tries = 0; tries < 8; ++tries) {
    long GTl = 0;
    for (int i = 0; i < 50; ++i) {
      const int k = 3 + 2 * i, nw = 224 / k, P = nw * nw, k2 = k * k;
      int R = i + 1; if (R < 2) R = 2; if (R > 20) R = 20;
      if (i <= 6) {
        const int lpl = (i <= 2) ? 0 : 2;
        const int LP = 1 << lpl, conc = 256 >> lpl;
        const long rc = (long)((k2 + LP - 1) / LP) * 2L * (12L * R + 8L);
        long np = T / rc; if (np < 1) np = 1;
        long cht = np * conc; if (cht > P) cht = P;
        int G = (int)(((long)P + cht - 1) / cht);
        int ch = (P + G - 1) / G; G = (P + ch - 1) / ch;
        G_[i] = G; CH_[i] = ch;
        bc[i] = (long)((ch + conc - 1) / conc) * rc;
      } else {
        const int ci = (i + 1 <= 24) ? (i - 7) : 17;
        const long trips = (long)((tab.ecnt[ci] + tab.mcnt[ci]) >> 6);
        const long ppc = trips * 340 + 1100;            // wave-cyc per patch
        long nppb = T / ppc; if (nppb < 4) nppb = 4;
        int cht = (int)(((nppb + 3) / 4) * 4); if (cht > P) cht = P;
        int G = (P + cht - 1) / cht;
        int ch = (P + G - 1) / G; G = (P + ch - 1) / ch;
        G_[i] = G; CH_[i] = ch;
        bc[i] = (long)((ch + 3) / 4) * ppc;
      }
      GTl += G_[i];
    }
    if (16L * GTl * 80L * 4L <= budget || tries == 7) break;
    T *= 2;
  }
  // heaviest blocks first
  int ord[50];
  for (int i = 0; i < 50; ++i) ord[i] = i;
  for (int a = 1; a < 50; ++a) {
    const int key = ord[a]; const long kw = bc[key];
    int bp = a - 1;
    while (bp >= 0 && bc[ord[bp]] < kw) { ord[bp + 1] = ord[bp]; --bp; }
    ord[bp + 1] = key;
  }
  tab.gpre[0] = 0;
  for (int j = 0; j < 50; ++j) {
    tab.kofseq[j] = ord[j];
    tab.gpre[j + 1] = tab.gpre[j] + G_[ord[j]];
  }
  for (int i = 0; i < 50; ++i) tab.CH[i] = CH_[i];
  tab.GT = tab.gpre[50];

  const float* x = (const float*)d_in[0];
  build_lists<<<36, 256, 0, stream>>>((uint32_t*)d_ws, tab);
  fractal_main<<<dim3(tab.GT, 16), 256, 0, stream>>>(x, (float*)d_ws, tab);
  fractal_final<<<800, 64, 0, stream>>>((const float*)d_ws, (float*)d_out, tab);
}